// Round 5
// baseline (220.359 us; speedup 1.0000x reference)
//
#include <hip/hip_runtime.h>
#include <hip/hip_fp16.h>
#include <math.h>

// Capsule routing, fused, register-resident, fp16-staged, d-split.
// 640 threads/block: thread = (j = wave 0..9, dhalf = bit5, ns = lane&31).
// Each thread owns out-dims d = dhalf*8..+7 of out-cap j, group ns.
// t/ua (9 floats) identical in both dhalf lanes (merged via shfl_xor 32);
// ps/bcv/W-rows are 8-wide per thread -> no spill at <=102 VGPR (5 waves/EU,
// 2 blocks/CU). b[j,i] never materialized: b = ua·(x,1) (rank-9 in x).
// LDS 38.4 KB: fp16 x (k-paired half2, lane-stride-1), stat2, Ul (stride 12).

#define BSZ   512
#define C_IN  256
#define HW    36
#define NS    32
#define NOC   10
#define OD    16
#define ROUTE 3
#define NIC   1152
#define NT    640
#define USTR  12

__global__ __launch_bounds__(256) void convert_w(
    const float* __restrict__ Wc, const float* __restrict__ bc,
    __half* __restrict__ w16)   // [40960 W | 5120 bias]
{
    const int n = 40960 + 5120;
    for (int i = blockIdx.x * 256 + threadIdx.x; i < n; i += gridDim.x * 256) {
        float v = (i < 40960) ? Wc[i] : bc[i - 40960];
        w16[i] = __float2half(v);
    }
}

__global__ __launch_bounds__(NT, 5) void caps_kernel(
    const float*  __restrict__ x,     // [BSZ, 256, 36] fp32
    const __half* __restrict__ w16,   // [5120, 8] fp16
    const __half* __restrict__ bc16,  // [5120] fp16
    float* __restrict__ out)          // [BSZ, 10, 16] fp32
{
    __shared__ __half2 xs2[4 * NIC];      // 18432 B: xs2[k2][p*32+ns]
    __shared__ float   stat2[NIC];        //  4608 B: logsumexp over j, idx p*32+ns
    __shared__ float   Ul[NOC*NS*USTR];   // 15360 B: Uacc mirror, row j*32+ns
    // total 38400 B -> 2 blocks/CU at 10 waves each = 20 waves/CU

    const int tid = threadIdx.x;
    const float* xb = x + (size_t)blockIdx.x * (C_IN * HW);

    // ---- Stage x -> fp16 LDS (task = channel-pair c2, float4-col p4) ----
    for (int t5 = tid; t5 < 128 * 9; t5 += NT) {
        int c2 = t5 / 9, p4 = t5 % 9;
        float4 a = *(const float4*)(xb + (2 * c2) * HW + p4 * 4);
        float4 b = *(const float4*)(xb + (2 * c2 + 1) * HW + p4 * 4);
        int nsc = c2 >> 2, k2 = c2 & 3;
        int base = k2 * NIC + (p4 * 4) * 32 + nsc;
        xs2[base +  0] = __floats2half2_rn(a.x, b.x);
        xs2[base + 32] = __floats2half2_rn(a.y, b.y);
        xs2[base + 64] = __floats2half2_rn(a.z, b.z);
        xs2[base + 96] = __floats2half2_rn(a.w, b.w);
    }
    __syncthreads();

    const int j     = tid >> 6;         // 0..9 (= wave index)
    const int dhalf = (tid >> 5) & 1;   // which 8 of the 16 out-dims
    const int ns    = tid & 31;

    const __half* wbase = w16 + (size_t)(ns * 160 + j * 16 + dhalf * 8) * 8;
    float bcv[8];
    {
        uint4 bv = *(const uint4*)(bc16 + ns * 160 + j * 16 + dhalf * 8);
        float2 b0 = __half22float2(*(__half2*)&bv.x);
        float2 b1 = __half22float2(*(__half2*)&bv.y);
        float2 b2 = __half22float2(*(__half2*)&bv.z);
        float2 b3 = __half22float2(*(__half2*)&bv.w);
        bcv[0]=b0.x; bcv[1]=b0.y; bcv[2]=b1.x; bcv[3]=b1.y;
        bcv[4]=b2.x; bcv[5]=b2.y; bcv[6]=b3.x; bcv[7]=b3.y;
    }

    float ua[9];   // cumulative routing coefficients (valid after it 0)

    for (int it = 0; it < ROUTE; ++it) {
        // ---- Phase A: stat2[i] = logsumexp_j ( Ul[j, ns_i]·(x_i,1) ) ----
        if (it > 0) {
            for (int i = tid; i < NIC; i += NT) {
                float2 f0 = __half22float2(xs2[0 * NIC + i]);
                float2 f1 = __half22float2(xs2[1 * NIC + i]);
                float2 f2 = __half22float2(xs2[2 * NIC + i]);
                float2 f3 = __half22float2(xs2[3 * NIC + i]);
                const int a = i & 31;
                float bv[NOC], mx = -1e30f;
                #pragma unroll
                for (int jj = 0; jj < NOC; ++jj) {
                    const float* up = &Ul[(jj * 32 + a) * USTR];
                    float4 u0 = *(const float4*)up;
                    float4 u1 = *(const float4*)(up + 4);
                    float bb = up[8]
                        + u0.x*f0.x + u0.y*f0.y + u0.z*f1.x + u0.w*f1.y
                        + u1.x*f2.x + u1.y*f2.y + u1.z*f3.x + u1.w*f3.y;
                    bv[jj] = bb; mx = fmaxf(mx, bb);
                }
                float se = 0.f;
                #pragma unroll
                for (int jj = 0; jj < NOC; ++jj) se += __expf(bv[jj] - mx);
                stat2[i] = mx + __logf(se);
            }
            __syncthreads();
        }

        // ---- Phase B: t[k] = sum_p c*x[k,p] over own 18 p's, merge pair ----
        float t[9];
        #pragma unroll
        for (int kk = 0; kk < 9; ++kk) t[kk] = 0.f;
        const int p0 = dhalf * 18;
        if (it == 0) {
            for (int pp = 0; pp < 18; ++pp) {
                int row = (p0 + pp) * 32 + ns;
                float2 f0 = __half22float2(xs2[0 * NIC + row]);
                float2 f1 = __half22float2(xs2[1 * NIC + row]);
                float2 f2 = __half22float2(xs2[2 * NIC + row]);
                float2 f3 = __half22float2(xs2[3 * NIC + row]);
                t[0] += f0.x; t[1] += f0.y; t[2] += f1.x; t[3] += f1.y;
                t[4] += f2.x; t[5] += f2.y; t[6] += f3.x; t[7] += f3.y;
            }
            #pragma unroll
            for (int kk = 0; kk < 8; ++kk) {
                t[kk] += __shfl_xor(t[kk], 32);
                t[kk] *= 0.1f;
            }
            t[8] = 3.6f;
        } else {
            for (int pp = 0; pp < 18; ++pp) {
                int row = (p0 + pp) * 32 + ns;
                float2 f0 = __half22float2(xs2[0 * NIC + row]);
                float2 f1 = __half22float2(xs2[1 * NIC + row]);
                float2 f2 = __half22float2(xs2[2 * NIC + row]);
                float2 f3 = __half22float2(xs2[3 * NIC + row]);
                float bb = ua[8]
                    + ua[0]*f0.x + ua[1]*f0.y + ua[2]*f1.x + ua[3]*f1.y
                    + ua[4]*f2.x + ua[5]*f2.y + ua[6]*f3.x + ua[7]*f3.y;
                float c = __expf(bb - stat2[row]);
                t[0] += c*f0.x; t[1] += c*f0.y; t[2] += c*f1.x; t[3] += c*f1.y;
                t[4] += c*f2.x; t[5] += c*f2.y; t[6] += c*f3.x; t[7] += c*f3.y;
                t[8] += c;
            }
            #pragma unroll
            for (int kk = 0; kk < 9; ++kk) t[kk] += __shfl_xor(t[kk], 32);
        }

        // ---- Phase C: ps[dd] = W·t + bcv*cs (own 8 d's); butterfly over ns ----
        float ps[8];
        #pragma unroll
        for (int dd = 0; dd < 8; ++dd) {
            uint4 wv = *(const uint4*)(wbase + (size_t)dd * 8);
            float2 w0 = __half22float2(*(__half2*)&wv.x);
            float2 w1 = __half22float2(*(__half2*)&wv.y);
            float2 w2 = __half22float2(*(__half2*)&wv.z);
            float2 w3 = __half22float2(*(__half2*)&wv.w);
            ps[dd] = w0.x*t[0] + w0.y*t[1] + w1.x*t[2] + w1.y*t[3]
                   + w2.x*t[4] + w2.y*t[5] + w3.x*t[6] + w3.y*t[7]
                   + bcv[dd] * t[8];
        }
        #pragma unroll
        for (int mk = 1; mk < 32; mk <<= 1) {
            #pragma unroll
            for (int dd = 0; dd < 8; ++dd)
                ps[dd] += __shfl_xor(ps[dd], mk);
        }
        float ssp = 0.f;
        #pragma unroll
        for (int dd = 0; dd < 8; ++dd) ssp += ps[dd] * ps[dd];
        float ss = ssp + __shfl_xor(ssp, 32);
        float fc = sqrtf(ss) / (1.f + ss);

        if (it == ROUTE - 1) {
            if (ns == 0) {
                float* o = out + (size_t)blockIdx.x * (NOC * OD) + j * OD + dhalf * 8;
                *(float4*)o       = make_float4(ps[0]*fc, ps[1]*fc, ps[2]*fc, ps[3]*fc);
                *(float4*)(o + 4) = make_float4(ps[4]*fc, ps[5]*fc, ps[6]*fc, ps[7]*fc);
            }
            break;
        }

        // ---- Phase D: u[k] = sum_d v[d]*W[r,k] (own 8 d's); merge pair ----
        float u[9];
        #pragma unroll
        for (int kk = 0; kk < 9; ++kk) u[kk] = 0.f;
        #pragma unroll
        for (int dd = 0; dd < 8; ++dd) {
            float vv = ps[dd] * fc;
            uint4 wv = *(const uint4*)(wbase + (size_t)dd * 8);
            float2 w0 = __half22float2(*(__half2*)&wv.x);
            float2 w1 = __half22float2(*(__half2*)&wv.y);
            float2 w2 = __half22float2(*(__half2*)&wv.z);
            float2 w3 = __half22float2(*(__half2*)&wv.w);
            u[0] += vv*w0.x; u[1] += vv*w0.y; u[2] += vv*w1.x; u[3] += vv*w1.y;
            u[4] += vv*w2.x; u[5] += vv*w2.y; u[6] += vv*w3.x; u[7] += vv*w3.y;
            u[8] += vv*bcv[dd];
        }
        #pragma unroll
        for (int kk = 0; kk < 9; ++kk) u[kk] += __shfl_xor(u[kk], 32);
        if (it == 0) {
            #pragma unroll
            for (int kk = 0; kk < 9; ++kk) ua[kk] = u[kk];
        } else {
            #pragma unroll
            for (int kk = 0; kk < 9; ++kk) ua[kk] += u[kk];
        }
        if (dhalf == 0) {
            float* up = &Ul[(j * 32 + ns) * USTR];
            *(float4*)up       = make_float4(ua[0], ua[1], ua[2], ua[3]);
            *(float4*)(up + 4) = make_float4(ua[4], ua[5], ua[6], ua[7]);
            up[8] = ua[8];
        }
        __syncthreads();
    }
}

extern "C" void kernel_launch(void* const* d_in, const int* in_sizes, int n_in,
                              void* d_out, int out_size, void* d_ws, size_t ws_size,
                              hipStream_t stream) {
    const float* x  = (const float*)d_in[0];
    // d_in[1] = target (int32) — unused in forward
    const float* Wc = (const float*)d_in[2];
    const float* bc = (const float*)d_in[3];
    float* out = (float*)d_out;

    __half* w16 = (__half*)d_ws;        // 40960 W halfs + 5120 bias halfs = 92160 B
    convert_w<<<dim3(48), dim3(256), 0, stream>>>(Wc, bc, w16);
    caps_kernel<<<dim3(BSZ), dim3(NT), 0, stream>>>(x, w16, w16 + 40960, out);
}

// Round 6
// 137.824 us; speedup vs baseline: 1.5988x; 1.5988x over previous
//
#include <hip/hip_runtime.h>
#include <hip/hip_fp16.h>
#include <math.h>

// Capsule routing, fused, register-resident, fp16-staged, d-split.
// 640 threads/block: thread = (j = wave 0..9, dhalf = bit5, ns = lane&31).
// Each thread owns out-dims d = dhalf*8..+7 of out-cap j, group ns; dhalf
// pairs merge via shfl_xor(·,32). b[j,i] never materialized (b = ua·(x,1),
// rank-9 in x). LDS: fp16 x (k-paired half2, lane-stride-1), stat2,
// Ul TRANSPOSED [9][320] so all Ul access is lane-stride-1 b32 (conflict-free;
// upper half-wave reads identical addresses -> broadcast).
// NOTE: __launch_bounds__ 2nd arg >=5 clamps VGPR to 48 on this toolchain
// (R4/R5 spill cascades). Keep it at 2: compiler uses ~100 VGPR, no spill.

#define BSZ   512
#define C_IN  256
#define HW    36
#define NS    32
#define NOC   10
#define OD    16
#define ROUTE 3
#define NIC   1152
#define NT    640

__global__ __launch_bounds__(256) void convert_w(
    const float* __restrict__ Wc, const float* __restrict__ bc,
    __half* __restrict__ w16)   // [40960 W | 5120 bias]
{
    const int n = 40960 + 5120;
    for (int i = blockIdx.x * 256 + threadIdx.x; i < n; i += gridDim.x * 256) {
        float v = (i < 40960) ? Wc[i] : bc[i - 40960];
        w16[i] = __float2half(v);
    }
}

__global__ __launch_bounds__(NT, 2) void caps_kernel(
    const float*  __restrict__ x,     // [BSZ, 256, 36] fp32
    const __half* __restrict__ w16,   // [5120, 8] fp16
    const __half* __restrict__ bc16,  // [5120] fp16
    float* __restrict__ out)          // [BSZ, 10, 16] fp32
{
    __shared__ __half2 xs2[4 * NIC];      // 18432 B: xs2[k2][p*32+ns]
    __shared__ float   stat2[NIC];        //  4608 B: logsumexp over j, idx p*32+ns
    __shared__ float   Ul[9 * NOC * NS];  // 11520 B: TRANSPOSED Ul[k][j*32+ns]
    // total 34560 B

    const int tid = threadIdx.x;
    const float* xb = x + (size_t)blockIdx.x * (C_IN * HW);

    // ---- Stage x -> fp16 LDS (task = channel-pair c2, float4-col p4) ----
    for (int t5 = tid; t5 < 128 * 9; t5 += NT) {
        int c2 = t5 / 9, p4 = t5 % 9;
        float4 a = *(const float4*)(xb + (2 * c2) * HW + p4 * 4);
        float4 b = *(const float4*)(xb + (2 * c2 + 1) * HW + p4 * 4);
        int nsc = c2 >> 2, k2 = c2 & 3;
        int base = k2 * NIC + (p4 * 4) * 32 + nsc;
        xs2[base +  0] = __floats2half2_rn(a.x, b.x);
        xs2[base + 32] = __floats2half2_rn(a.y, b.y);
        xs2[base + 64] = __floats2half2_rn(a.z, b.z);
        xs2[base + 96] = __floats2half2_rn(a.w, b.w);
    }
    __syncthreads();

    const int j     = tid >> 6;         // 0..9 (= wave index)
    const int dhalf = (tid >> 5) & 1;   // which 8 of the 16 out-dims
    const int ns    = tid & 31;

    const __half* wbase = w16 + (size_t)(ns * 160 + j * 16 + dhalf * 8) * 8;
    float bcv[8];
    {
        uint4 bv = *(const uint4*)(bc16 + ns * 160 + j * 16 + dhalf * 8);
        float2 b0 = __half22float2(*(__half2*)&bv.x);
        float2 b1 = __half22float2(*(__half2*)&bv.y);
        float2 b2 = __half22float2(*(__half2*)&bv.z);
        float2 b3 = __half22float2(*(__half2*)&bv.w);
        bcv[0]=b0.x; bcv[1]=b0.y; bcv[2]=b1.x; bcv[3]=b1.y;
        bcv[4]=b2.x; bcv[5]=b2.y; bcv[6]=b3.x; bcv[7]=b3.y;
    }

    float ua[9];   // cumulative routing coefficients (valid after it 0)

    for (int it = 0; it < ROUTE; ++it) {
        // ---- Phase A: stat2[i] = logsumexp_j ( Ul[:, j, ns_i]·(x_i,1) ) ----
        if (it > 0) {
            for (int i = tid; i < NIC; i += NT) {
                float2 f0 = __half22float2(xs2[0 * NIC + i]);
                float2 f1 = __half22float2(xs2[1 * NIC + i]);
                float2 f2 = __half22float2(xs2[2 * NIC + i]);
                float2 f3 = __half22float2(xs2[3 * NIC + i]);
                const int a = i & 31;
                float bv[NOC], mx = -1e30f;
                #pragma unroll
                for (int jj = 0; jj < NOC; ++jj) {
                    const int col = jj * 32 + a;
                    float bb = Ul[8 * 320 + col]
                        + Ul[0*320+col]*f0.x + Ul[1*320+col]*f0.y
                        + Ul[2*320+col]*f1.x + Ul[3*320+col]*f1.y
                        + Ul[4*320+col]*f2.x + Ul[5*320+col]*f2.y
                        + Ul[6*320+col]*f3.x + Ul[7*320+col]*f3.y;
                    bv[jj] = bb; mx = fmaxf(mx, bb);
                }
                float se = 0.f;
                #pragma unroll
                for (int jj = 0; jj < NOC; ++jj) se += __expf(bv[jj] - mx);
                stat2[i] = mx + __logf(se);
            }
            __syncthreads();
        }

        // ---- Phase B: t[k] = sum_p c*x[k,p] over own 18 p's, merge pair ----
        float t[9];
        #pragma unroll
        for (int kk = 0; kk < 9; ++kk) t[kk] = 0.f;
        const int p0 = dhalf * 18;
        if (it == 0) {
            for (int pp = 0; pp < 18; ++pp) {
                int row = (p0 + pp) * 32 + ns;
                float2 f0 = __half22float2(xs2[0 * NIC + row]);
                float2 f1 = __half22float2(xs2[1 * NIC + row]);
                float2 f2 = __half22float2(xs2[2 * NIC + row]);
                float2 f3 = __half22float2(xs2[3 * NIC + row]);
                t[0] += f0.x; t[1] += f0.y; t[2] += f1.x; t[3] += f1.y;
                t[4] += f2.x; t[5] += f2.y; t[6] += f3.x; t[7] += f3.y;
            }
            #pragma unroll
            for (int kk = 0; kk < 8; ++kk) {
                t[kk] += __shfl_xor(t[kk], 32);
                t[kk] *= 0.1f;
            }
            t[8] = 3.6f;
        } else {
            for (int pp = 0; pp < 18; ++pp) {
                int row = (p0 + pp) * 32 + ns;
                float2 f0 = __half22float2(xs2[0 * NIC + row]);
                float2 f1 = __half22float2(xs2[1 * NIC + row]);
                float2 f2 = __half22float2(xs2[2 * NIC + row]);
                float2 f3 = __half22float2(xs2[3 * NIC + row]);
                float bb = ua[8]
                    + ua[0]*f0.x + ua[1]*f0.y + ua[2]*f1.x + ua[3]*f1.y
                    + ua[4]*f2.x + ua[5]*f2.y + ua[6]*f3.x + ua[7]*f3.y;
                float c = __expf(bb - stat2[row]);
                t[0] += c*f0.x; t[1] += c*f0.y; t[2] += c*f1.x; t[3] += c*f1.y;
                t[4] += c*f2.x; t[5] += c*f2.y; t[6] += c*f3.x; t[7] += c*f3.y;
                t[8] += c;
            }
            #pragma unroll
            for (int kk = 0; kk < 9; ++kk) t[kk] += __shfl_xor(t[kk], 32);
        }

        // ---- Phase C: ps[dd] = W·t + bcv*cs (own 8 d's); butterfly over ns ----
        float ps[8];
        #pragma unroll
        for (int dd = 0; dd < 8; ++dd) {
            uint4 wv = *(const uint4*)(wbase + (size_t)dd * 8);
            float2 w0 = __half22float2(*(__half2*)&wv.x);
            float2 w1 = __half22float2(*(__half2*)&wv.y);
            float2 w2 = __half22float2(*(__half2*)&wv.z);
            float2 w3 = __half22float2(*(__half2*)&wv.w);
            ps[dd] = w0.x*t[0] + w0.y*t[1] + w1.x*t[2] + w1.y*t[3]
                   + w2.x*t[4] + w2.y*t[5] + w3.x*t[6] + w3.y*t[7]
                   + bcv[dd] * t[8];
        }
        #pragma unroll
        for (int mk = 1; mk < 32; mk <<= 1) {
            #pragma unroll
            for (int dd = 0; dd < 8; ++dd)
                ps[dd] += __shfl_xor(ps[dd], mk);
        }
        float ssp = 0.f;
        #pragma unroll
        for (int dd = 0; dd < 8; ++dd) ssp += ps[dd] * ps[dd];
        float ss = ssp + __shfl_xor(ssp, 32);
        float fc = sqrtf(ss) / (1.f + ss);

        if (it == ROUTE - 1) {
            if (ns == 0) {
                float* o = out + (size_t)blockIdx.x * (NOC * OD) + j * OD + dhalf * 8;
                *(float4*)o       = make_float4(ps[0]*fc, ps[1]*fc, ps[2]*fc, ps[3]*fc);
                *(float4*)(o + 4) = make_float4(ps[4]*fc, ps[5]*fc, ps[6]*fc, ps[7]*fc);
            }
            break;
        }

        // ---- Phase D: u[k] = sum_d v[d]*W[r,k] (own 8 d's); merge pair ----
        float u[9];
        #pragma unroll
        for (int kk = 0; kk < 9; ++kk) u[kk] = 0.f;
        #pragma unroll
        for (int dd = 0; dd < 8; ++dd) {
            float vv = ps[dd] * fc;
            uint4 wv = *(const uint4*)(wbase + (size_t)dd * 8);
            float2 w0 = __half22float2(*(__half2*)&wv.x);
            float2 w1 = __half22float2(*(__half2*)&wv.y);
            float2 w2 = __half22float2(*(__half2*)&wv.z);
            float2 w3 = __half22float2(*(__half2*)&wv.w);
            u[0] += vv*w0.x; u[1] += vv*w0.y; u[2] += vv*w1.x; u[3] += vv*w1.y;
            u[4] += vv*w2.x; u[5] += vv*w2.y; u[6] += vv*w3.x; u[7] += vv*w3.y;
            u[8] += vv*bcv[dd];
        }
        #pragma unroll
        for (int kk = 0; kk < 9; ++kk) u[kk] += __shfl_xor(u[kk], 32);
        if (it == 0) {
            #pragma unroll
            for (int kk = 0; kk < 9; ++kk) ua[kk] = u[kk];
        } else {
            #pragma unroll
            for (int kk = 0; kk < 9; ++kk) ua[kk] += u[kk];
        }
        if (dhalf == 0) {
            #pragma unroll
            for (int kk = 0; kk < 9; ++kk)
                Ul[kk * 320 + j * 32 + ns] = ua[kk];
        }
        __syncthreads();
    }
}

extern "C" void kernel_launch(void* const* d_in, const int* in_sizes, int n_in,
                              void* d_out, int out_size, void* d_ws, size_t ws_size,
                              hipStream_t stream) {
    const float* x  = (const float*)d_in[0];
    // d_in[1] = target (int32) — unused in forward
    const float* Wc = (const float*)d_in[2];
    const float* bc = (const float*)d_in[3];
    float* out = (float*)d_out;

    __half* w16 = (__half*)d_ws;        // 40960 W halfs + 5120 bias halfs = 92160 B
    convert_w<<<dim3(48), dim3(256), 0, stream>>>(Wc, bc, w16);
    caps_kernel<<<dim3(BSZ), dim3(NT), 0, stream>>>(x, w16, w16 + 40960, out);
}